// Round 18
// baseline (103.025 us; speedup 1.0000x reference)
//
#include <hip/hip_runtime.h>

#define BT 48
#define NN 2048
#define FF 64
#define EE 32768
#define ROWS (BT*NN)          // 98304
#define PROJ_BLKS 1536        // 64 rows each (R10's best-measured proj geometry)
#define CSR_BLKS 64

typedef __attribute__((ext_vector_type(2))) _Float16 half2v;
typedef __attribute__((ext_vector_type(8))) _Float16 half8v;
typedef __attribute__((ext_vector_type(4))) float float4v;

__device__ __forceinline__ unsigned cvt2h(float lo, float hi){
    union { half2v h; unsigned u; } c;
    c.h = half2v{(_Float16)lo, (_Float16)hi};
    return c.u;
}
__device__ __forceinline__ half2v h2(unsigned u){
    union { unsigned u; half2v h; } c; c.u = u; return c.h;
}

union FragH { unsigned u[4]; half8v h; uint4 u4; };

// ---------------- Kernel 0: W fragment pre-pack (+ meta zero) ----------
__global__ __launch_bounds__(256) void wpack_kernel(
    const float* __restrict__ Wk, const float* __restrict__ Wq,
    const float* __restrict__ Wv, const float* __restrict__ Ws,
    unsigned* __restrict__ Wp, int* __restrict__ meta)
{
    const int t = threadIdx.x;
    if (t < 8) meta[t] = 0;
    for (int idx = t; idx < 8192; idx += 256){
        const int mat = idx >> 11;
        const int r   = idx & 2047;
        const int ft  = r >> 9;
        const int h   = (r >> 8) & 1;
        const int l   = (r >> 2) & 63;
        const int jj  = r & 3;
        const float* W = (mat==0)?Wk:(mat==1)?Wq:(mat==2)?Wv:Ws;
        const int k0 = h*32 + (l>>4)*8 + 2*jj;
        const int c  = ft*16 + (l&15);
        Wp[idx] = cvt2h(W[(size_t)k0*FF + c], W[(size_t)(k0+1)*FF + c]);
    }
}

// ---------------- Kernel 1: proj (0..1535, 64 rows) + CSR (1536..1599) --
// ONE matrix per wave (w -> K,Q,V,skip): fragment footprint = 32 VGPRs
// (vs 64 for the 2-mat variants, which pinned VGPR_Count=64 and forced
// in-loop W rematerialization at L2 latency -- R11-R17's 46-52us plateau).
// R10 measured this geometry standalone at 42.5us (VGPR=88). Q wave writes
// even QV dword slots, V wave odd slots (no LDS exchange needed).
// CSR blocks trail at 1536+: proj never waits, so they always get placed;
// gbar only among the 64 CSR blocks.
__device__ __forceinline__ void gbar(int* ctr, int nblk){
    __syncthreads();
    if (threadIdx.x == 0){
        __threadfence();
        atomicAdd(ctr, 1);
        while (__hip_atomic_load(ctr, __ATOMIC_ACQUIRE, __HIP_MEMORY_SCOPE_AGENT) < nblk) {}
    }
    __syncthreads();
}

__global__ __launch_bounds__(256) void projcsr_kernel(
    const float* __restrict__ x, const unsigned* __restrict__ Wp,
    const float* __restrict__ bk, const float* __restrict__ bq,
    const float* __restrict__ bv, const float* __restrict__ bs,
    unsigned* __restrict__ Kh, unsigned* __restrict__ QV,
    float* __restrict__ out,
    const unsigned int* __restrict__ ew,
    int* __restrict__ flag, int* __restrict__ bar,
    int* __restrict__ deg, int* __restrict__ offs,
    int* __restrict__ cur, int* __restrict__ elist)
{
    __shared__ int wsums[4];

    if (blockIdx.x >= PROJ_BLKS){
        // ---------------- CSR part ----------------
        const int t = threadIdx.x;
        const int gtid = (blockIdx.x - PROJ_BLKS)*256 + t;   // 16384 threads

        for (int i=gtid; i<NN; i+=16384) deg[i] = 0;
        if (gtid < 16) elist[EE + gtid] = 0;
        unsigned f = 0;
        for (int i=gtid; i<8192; i+=16384) f |= ew[2*i+1];
        if (f) atomicOr((unsigned int*)flag, f);
        gbar(bar+0, CSR_BLKS);
        const bool i64 = (*flag == 0);

        for (int e=gtid; e<EE; e+=16384){
            const int d = i64 ? (int)ew[2*(EE+e)] : (int)ew[EE+e];
            atomicAdd(&deg[d], 1);
        }
        gbar(bar+1, CSR_BLKS);

        if (blockIdx.x == PROJ_BLKS){
            const int base = t*8;
            int v[8], pre[8];
            #pragma unroll
            for (int j=0;j<8;j++) v[j] = deg[base+j];
            pre[0] = 0;
            #pragma unroll
            for (int j=1;j<8;j++) pre[j] = pre[j-1] + v[j-1];
            const int s = pre[7] + v[7];
            int inc = s;
            const int lane = t & 63, wid = t >> 6;
            #pragma unroll
            for (int d=1; d<64; d<<=1){ int tt = __shfl_up(inc, d, 64); if (lane>=d) inc += tt; }
            if (lane == 63) wsums[wid] = inc;
            __syncthreads();
            if (t == 0){ int a=0; for (int k2=0;k2<4;k2++){ int tt=wsums[k2]; wsums[k2]=a; a+=tt; } }
            __syncthreads();
            const int excl = wsums[wid] + (inc - s);
            #pragma unroll
            for (int j=0;j<8;j++){ offs[base+j] = excl + pre[j]; cur[base+j] = excl + pre[j]; }
            if (t == 255) offs[NN] = excl + s;
        }
        gbar(bar+2, CSR_BLKS);

        for (int e=gtid; e<EE; e+=16384){
            int d, s;
            if (i64){ d = (int)ew[2*(EE+e)]; s = (int)ew[2*e]; }
            else    { d = (int)ew[EE+e];     s = (int)ew[e];   }
            const int pos = atomicAdd(&cur[d], 1);
            elist[pos] = s;
        }
        return;
    }

    // ---------------- proj part (one matrix per wave) ----------------
    const int tid = threadIdx.x;
    const int w  = tid >> 6;              // wave -> matrix (0:K 1:Q 2:V 3:skip)
    const int l  = tid & 63;
    const int lr = l & 15;
    const int lh = l >> 4;
    const float* bm = (w==0)?bk:(w==1)?bq:(w==2)?bv:bs;

    FragH af[4][2];                       // 32 VGPRs -- fits, no clamp
    #pragma unroll
    for (int ft=0;ft<4;ft++)
        #pragma unroll
        for (int h=0;h<2;h++)
            af[ft][h].u4 = *(const uint4*)(Wp + ((w*4+ft)*2+h)*256 + l*4);

    float4 bias4[4];
    #pragma unroll
    for (int ft=0;ft<4;ft++) bias4[ft] = *(const float4*)(bm + ft*16 + lh*4);

    const int row0 = blockIdx.x * 64;
    #pragma unroll 2
    for (int rt=0; rt<4; ++rt){
        const int r16 = row0 + rt*16;
        const float* xr = x + (size_t)(r16 + lr)*FF + lh*8;
        const float4 xa0 = *(const float4*)(xr);
        const float4 xa1 = *(const float4*)(xr + 4);
        const float4 xb0 = *(const float4*)(xr + 32);
        const float4 xb1 = *(const float4*)(xr + 36);
        FragH b0, b1;
        b0.u[0]=cvt2h(xa0.x,xa0.y); b0.u[1]=cvt2h(xa0.z,xa0.w);
        b0.u[2]=cvt2h(xa1.x,xa1.y); b0.u[3]=cvt2h(xa1.z,xa1.w);
        b1.u[0]=cvt2h(xb0.x,xb0.y); b1.u[1]=cvt2h(xb0.z,xb0.w);
        b1.u[2]=cvt2h(xb1.x,xb1.y); b1.u[3]=cvt2h(xb1.z,xb1.w);

        const size_t row = (size_t)(r16 + lr);
        #pragma unroll
        for (int ft=0;ft<4;ft++){
            float4v acc = float4v{bias4[ft].x, bias4[ft].y, bias4[ft].z, bias4[ft].w};
            acc = __builtin_amdgcn_mfma_f32_16x16x32_f16(af[ft][0].h, b0.h, acc, 0,0,0);
            acc = __builtin_amdgcn_mfma_f32_16x16x32_f16(af[ft][1].h, b1.h, acc, 0,0,0);
            const int p0 = ft*8 + lh*2;
            if (w == 0){
                uint2 st; st.x = cvt2h(acc[0],acc[1]); st.y = cvt2h(acc[2],acc[3]);
                *(uint2*)(Kh + row*32 + p0) = st;
            } else if (w == 1){           // q pairs at even u32 slots
                QV[row*FF + 2*p0]     = cvt2h(acc[0],acc[1]);
                QV[row*FF + 2*(p0+1)] = cvt2h(acc[2],acc[3]);
            } else if (w == 2){           // v pairs at odd u32 slots
                QV[row*FF + 2*p0 + 1]     = cvt2h(acc[0],acc[1]);
                QV[row*FF + 2*(p0+1) + 1] = cvt2h(acc[2],acc[3]);
            } else {
                *(float4*)(out + row*FF + ft*16 + lh*4) =
                    make_float4(acc[0],acc[1],acc[2],acc[3]);
            }
        }
    }
}

// ---------------- Kernel 2: gather + gate + aggregate (fp16, 2 bt/wave) --
#define HEDGE2(U, KA, KB, A01, A23) { \
    half2v g01 = (KA) + h2((U).x); \
    g01 = __builtin_elementwise_max(g01, g01*c001); \
    (A01) += g01 * h2((U).y); \
    half2v g23 = (KB) + h2((U).z); \
    g23 = __builtin_elementwise_max(g23, g23*c001); \
    (A23) += g23 * h2((U).w); }
#define HEDGE2M(U, KA, KB, A01, A23, M) { \
    half2v g01 = (KA) + h2((U).x); \
    g01 = __builtin_elementwise_max(g01, g01*c001); \
    (A01) += g01 * (h2((U).y) * (M)); \
    half2v g23 = (KB) + h2((U).z); \
    g23 = __builtin_elementwise_max(g23, g23*c001); \
    (A23) += g23 * (h2((U).w) * (M)); }

__global__ __launch_bounds__(256) void agg_kernel(
    const unsigned* __restrict__ Kh, const unsigned* __restrict__ QV,
    const int* __restrict__ offs, const int* __restrict__ elist,
    float* __restrict__ out)
{
    const int tid  = threadIdx.x;
    const int lane = tid & 63;
    const int w    = tid >> 6;
    const int b    = blockIdx.x;          // 12288 blocks
    const int xcd  = b & 7;
    const int li   = b >> 3;              // 0..1535
    const int pr   = xcd*3 + (li >> 9);   // bt pair 0..23
    const int node = ((li & 511) << 2) | w;
    const int sub  = lane >> 4;
    const int fq   = lane & 15;
    const int bt0  = pr*2;
    const size_t S = (size_t)NN*FF;

    const uint2 ku0 = *(const uint2*)(Kh + ((size_t)bt0*NN + node)*32 + 2*fq);
    const uint2 ku1 = *(const uint2*)(Kh + ((size_t)(bt0+1)*NN + node)*32 + 2*fq);
    const size_t r0 = ((size_t)bt0*NN + node)*FF;
    const size_t r1 = r0 + S;
    const float4 sk0 = *(const float4*)(out + r0 + fq*4);
    const float4 sk1 = *(const float4*)(out + r1 + fq*4);

    const half2v k01a = h2(ku0.x), k23a = h2(ku0.y);
    const half2v k01b = h2(ku1.x), k23b = h2(ku1.y);
    const half2v c001 = half2v{(_Float16)0.01f, (_Float16)0.01f};
    const half2v one2 = half2v{(_Float16)1.f, (_Float16)1.f};
    const half2v zero2 = half2v{(_Float16)0.f, (_Float16)0.f};
    const unsigned* QV0 = QV + (size_t)bt0*S;
    const unsigned* QV1 = QV0 + S;

    half2v a01_0 = zero2, a23_0 = zero2;  // bt0
    half2v a01_1 = zero2, a23_1 = zero2;  // bt1
    const int s0 = offs[node], s1 = offs[node+1];

    for (int i = s0; i < s1; i += 16){
        const int rem  = s1 - i;          // wave-uniform
        const int4 ev = *(const int4*)(elist + i + 4*sub);
        const unsigned o0 = (((unsigned)ev.x)<<6) + (fq<<2);
        const unsigned o1 = (((unsigned)ev.y)<<6) + (fq<<2);
        const unsigned o2 = (((unsigned)ev.z)<<6) + (fq<<2);
        const unsigned o3 = (((unsigned)ev.w)<<6) + (fq<<2);
        const uint4 u00 = *(const uint4*)(QV0 + o0);
        const uint4 u10 = *(const uint4*)(QV1 + o0);
        const uint4 u01 = *(const uint4*)(QV0 + o1);
        const uint4 u11 = *(const uint4*)(QV1 + o1);
        const uint4 u02 = *(const uint4*)(QV0 + o2);
        const uint4 u12 = *(const uint4*)(QV1 + o2);
        const uint4 u03 = *(const uint4*)(QV0 + o3);
        const uint4 u13 = *(const uint4*)(QV1 + o3);
        if (rem >= 16){
            HEDGE2(u00, k01a, k23a, a01_0, a23_0); HEDGE2(u10, k01b, k23b, a01_1, a23_1);
            HEDGE2(u01, k01a, k23a, a01_0, a23_0); HEDGE2(u11, k01b, k23b, a01_1, a23_1);
            HEDGE2(u02, k01a, k23a, a01_0, a23_0); HEDGE2(u12, k01b, k23b, a01_1, a23_1);
            HEDGE2(u03, k01a, k23a, a01_0, a23_0); HEDGE2(u13, k01b, k23b, a01_1, a23_1);
        } else {
            const half2v m0 = (4*sub+0 < rem) ? one2 : zero2;
            const half2v m1 = (4*sub+1 < rem) ? one2 : zero2;
            const half2v m2 = (4*sub+2 < rem) ? one2 : zero2;
            const half2v m3 = (4*sub+3 < rem) ? one2 : zero2;
            HEDGE2M(u00, k01a, k23a, a01_0, a23_0, m0); HEDGE2M(u10, k01b, k23b, a01_1, a23_1, m0);
            HEDGE2M(u01, k01a, k23a, a01_0, a23_0, m1); HEDGE2M(u11, k01b, k23b, a01_1, a23_1, m1);
            HEDGE2M(u02, k01a, k23a, a01_0, a23_0, m2); HEDGE2M(u12, k01b, k23b, a01_1, a23_1, m2);
            HEDGE2M(u03, k01a, k23a, a01_0, a23_0, m3); HEDGE2M(u13, k01b, k23b, a01_1, a23_1, m3);
        }
    }

    float4 ac0 = make_float4((float)a01_0[0], (float)a01_0[1],
                             (float)a23_0[0], (float)a23_0[1]);
    float4 ac1 = make_float4((float)a01_1[0], (float)a01_1[1],
                             (float)a23_1[0], (float)a23_1[1]);

    ac0.x += __shfl_xor(ac0.x, 16, 64); ac0.y += __shfl_xor(ac0.y, 16, 64);
    ac0.z += __shfl_xor(ac0.z, 16, 64); ac0.w += __shfl_xor(ac0.w, 16, 64);
    ac0.x += __shfl_xor(ac0.x, 32, 64); ac0.y += __shfl_xor(ac0.y, 32, 64);
    ac0.z += __shfl_xor(ac0.z, 32, 64); ac0.w += __shfl_xor(ac0.w, 32, 64);
    ac1.x += __shfl_xor(ac1.x, 16, 64); ac1.y += __shfl_xor(ac1.y, 16, 64);
    ac1.z += __shfl_xor(ac1.z, 16, 64); ac1.w += __shfl_xor(ac1.w, 16, 64);
    ac1.x += __shfl_xor(ac1.x, 32, 64); ac1.y += __shfl_xor(ac1.y, 32, 64);
    ac1.z += __shfl_xor(ac1.z, 32, 64); ac1.w += __shfl_xor(ac1.w, 32, 64);

    if (sub == 0){
        *(float4*)(out + r0 + fq*4) =
            make_float4(ac0.x+sk0.x, ac0.y+sk0.y, ac0.z+sk0.z, ac0.w+sk0.w);
        *(float4*)(out + r1 + fq*4) =
            make_float4(ac1.x+sk1.x, ac1.y+sk1.y, ac1.z+sk1.z, ac1.w+sk1.w);
    }
}

extern "C" void kernel_launch(void* const* d_in, const int* in_sizes, int n_in,
                              void* d_out, int out_size, void* d_ws, size_t ws_size,
                              hipStream_t stream)
{
    const float* x  = (const float*)d_in[0];
    const unsigned int* ew = (const unsigned int*)d_in[1];
    const float* Wk = (const float*)d_in[2];
    const float* bk = (const float*)d_in[3];
    const float* Wq = (const float*)d_in[4];
    const float* bq = (const float*)d_in[5];
    const float* Wv = (const float*)d_in[6];
    const float* bv = (const float*)d_in[7];
    const float* Ws = (const float*)d_in[8];
    const float* bs = (const float*)d_in[9];
    float* out = (float*)d_out;

    const size_t n = (size_t)ROWS*FF;
    unsigned* Kh = (unsigned*)d_ws;       // ROWS*32 u32
    unsigned* QV = Kh + (size_t)ROWS*32;  // ROWS*64 u32
    unsigned* Wp = QV + n;                // 8192 u32
    int* meta  = (int*)(Wp + 8192);
    int* flag  = meta;
    int* bar   = meta + 4;
    int* deg   = meta + 16;
    int* offs  = deg + NN;
    int* cur   = offs + NN + 16;
    int* elist = cur + NN;

    hipLaunchKernelGGL(wpack_kernel, dim3(1), dim3(256), 0, stream,
                       Wk, Wq, Wv, Ws, Wp, meta);
    hipLaunchKernelGGL(projcsr_kernel, dim3(PROJ_BLKS + CSR_BLKS), dim3(256), 0, stream,
                       x, Wp, bk, bq, bv, bs, Kh, QV, out,
                       ew, flag, bar, deg, offs, cur, elist);
    hipLaunchKernelGGL(agg_kernel, dim3(ROWS/8), dim3(256), 0, stream,
                       Kh, QV, offs, elist, out);
}

// Round 19
// 93.103 us; speedup vs baseline: 1.1066x; 1.1066x over previous
//
#include <hip/hip_runtime.h>

#define BT 48
#define NN 2048
#define FF 64
#define EE 32768
#define ROWS (BT*NN)          // 98304
#define PROJ_BLKS 768         // 128 rows each
#define CSR_BLKS 64
#define XPITCH 68             // LDS row pitch (floats): breaks 256B-stride bank conflicts

typedef __attribute__((ext_vector_type(2))) _Float16 half2v;
typedef __attribute__((ext_vector_type(8))) _Float16 half8v;
typedef __attribute__((ext_vector_type(4))) float float4v;

__device__ __forceinline__ unsigned cvt2h(float lo, float hi){
    union { half2v h; unsigned u; } c;
    c.h = half2v{(_Float16)lo, (_Float16)hi};
    return c.u;
}
__device__ __forceinline__ half2v h2(unsigned u){
    union { unsigned u; half2v h; } c; c.u = u; return c.h;
}

union FragH { unsigned u[4]; half8v h; uint4 u4; };

// ---------------- Kernel 0: W fragment pre-pack (+ meta zero) ----------
__global__ __launch_bounds__(256) void wpack_kernel(
    const float* __restrict__ Wk, const float* __restrict__ Wq,
    const float* __restrict__ Wv, const float* __restrict__ Ws,
    unsigned* __restrict__ Wp, int* __restrict__ meta)
{
    const int t = threadIdx.x;
    if (t < 8) meta[t] = 0;
    for (int idx = t; idx < 8192; idx += 256){
        const int mat = idx >> 11;
        const int r   = idx & 2047;
        const int ft  = r >> 9;
        const int h   = (r >> 8) & 1;
        const int l   = (r >> 2) & 63;
        const int jj  = r & 3;
        const float* W = (mat==0)?Wk:(mat==1)?Wq:(mat==2)?Wv:Ws;
        const int k0 = h*32 + (l>>4)*8 + 2*jj;
        const int c  = ft*16 + (l&15);
        Wp[idx] = cvt2h(W[(size_t)k0*FF + c], W[(size_t)(k0+1)*FF + c]);
    }
}

// ---------------- Kernel 1: proj (blocks 0..767) + CSR (768..831) -------
// Final configuration = R14/R17 (twice-verified 92.2-92.3us).
// Proj plateau ~48us is compiler-regalloc-bound: 6 structural variants
// (reg-W, LDS-x, VGPR caps, LDS-W, 64/128/256-row blocks, 1-mat/wave)
// all measured 42-62us; VGPR_Count never matched the requested footprint.
// CSR (no proj dependence) hides under proj. R16's cross-block spin
// pipeline collapsed the fabric (152GB/s) -- do not revisit without
// per-consumer cache lines + long backoff.
__device__ __forceinline__ void gbar(int* ctr, int nblk){
    __syncthreads();
    if (threadIdx.x == 0){
        __threadfence();
        atomicAdd(ctr, 1);
        while (__hip_atomic_load(ctr, __ATOMIC_ACQUIRE, __HIP_MEMORY_SCOPE_AGENT) < nblk) {}
    }
    __syncthreads();
}

__global__ __launch_bounds__(256, 4) void projcsr_kernel(
    const float* __restrict__ x, const unsigned* __restrict__ Wp,
    const float* __restrict__ bk, const float* __restrict__ bq,
    const float* __restrict__ bv, const float* __restrict__ bs,
    unsigned* __restrict__ Kh, unsigned* __restrict__ QV,
    float* __restrict__ out,
    const unsigned int* __restrict__ ew,
    int* __restrict__ flag, int* __restrict__ bar,
    int* __restrict__ deg, int* __restrict__ offs,
    int* __restrict__ cur, int* __restrict__ elist)
{
    __shared__ float xs[128*XPITCH];      // 34 KB
    __shared__ int wsums[4];

    if (blockIdx.x >= PROJ_BLKS){
        // ---------------- CSR part ----------------
        const int t = threadIdx.x;
        const int gtid = (blockIdx.x - PROJ_BLKS)*256 + t;   // 16384 threads

        for (int i=gtid; i<NN; i+=16384) deg[i] = 0;
        if (gtid < 16) elist[EE + gtid] = 0;
        unsigned f = 0;
        for (int i=gtid; i<8192; i+=16384) f |= ew[2*i+1];
        if (f) atomicOr((unsigned int*)flag, f);
        gbar(bar+0, CSR_BLKS);
        const bool i64 = (*flag == 0);

        for (int e=gtid; e<EE; e+=16384){
            const int d = i64 ? (int)ew[2*(EE+e)] : (int)ew[EE+e];
            atomicAdd(&deg[d], 1);
        }
        gbar(bar+1, CSR_BLKS);

        if (blockIdx.x == PROJ_BLKS){
            const int base = t*8;
            int v[8], pre[8];
            #pragma unroll
            for (int j=0;j<8;j++) v[j] = deg[base+j];
            pre[0] = 0;
            #pragma unroll
            for (int j=1;j<8;j++) pre[j] = pre[j-1] + v[j-1];
            const int s = pre[7] + v[7];
            int inc = s;
            const int lane = t & 63, wid = t >> 6;
            #pragma unroll
            for (int d=1; d<64; d<<=1){ int tt = __shfl_up(inc, d, 64); if (lane>=d) inc += tt; }
            if (lane == 63) wsums[wid] = inc;
            __syncthreads();
            if (t == 0){ int a=0; for (int k2=0;k2<4;k2++){ int tt=wsums[k2]; wsums[k2]=a; a+=tt; } }
            __syncthreads();
            const int excl = wsums[wid] + (inc - s);
            #pragma unroll
            for (int j=0;j<8;j++){ offs[base+j] = excl + pre[j]; cur[base+j] = excl + pre[j]; }
            if (t == 255) offs[NN] = excl + s;
        }
        gbar(bar+2, CSR_BLKS);

        for (int e=gtid; e<EE; e+=16384){
            int d, s;
            if (i64){ d = (int)ew[2*(EE+e)]; s = (int)ew[2*e]; }
            else    { d = (int)ew[EE+e];     s = (int)ew[e];   }
            const int pos = atomicAdd(&cur[d], 1);
            elist[pos] = s;
        }
        return;
    }

    // ---------------- proj part ----------------
    const int tid = threadIdx.x;
    const int w  = tid >> 6;
    const int l  = tid & 63;
    const int lr = l & 15;
    const int lh = l >> 4;
    const int wm = w & 1;                 // 0: K+skip, 1: Q+V
    const int matA = wm ? 1 : 0;          // Q : K
    const int matB = wm ? 2 : 3;          // V : skip
    const float* bmA = wm ? bq : bk;
    const float* bmB = wm ? bv : bs;

    // stage 128 rows of x into LDS (coalesced)
    {
        const float4* xg = (const float4*)(x + (size_t)blockIdx.x*128*FF);
        for (int i = tid; i < 128*16; i += 256){
            const int row = i >> 4, c4 = i & 15;
            *(float4*)(xs + row*XPITCH + c4*4) = xg[i];
        }
    }

    FragH afA[4][2], afB[4][2];
    #pragma unroll
    for (int ft=0;ft<4;ft++)
        #pragma unroll
        for (int h=0;h<2;h++){
            afA[ft][h].u4 = *(const uint4*)(Wp + ((matA*4+ft)*2+h)*256 + l*4);
            afB[ft][h].u4 = *(const uint4*)(Wp + ((matB*4+ft)*2+h)*256 + l*4);
        }
    float4 biasA[4], biasB[4];
    #pragma unroll
    for (int ft=0;ft<4;ft++){
        biasA[ft] = *(const float4*)(bmA + ft*16 + lh*4);
        biasB[ft] = *(const float4*)(bmB + ft*16 + lh*4);
    }
    __syncthreads();

    const int lrow0 = (w>>1)*64;
    #pragma unroll 2
    for (int rt=0; rt<4; ++rt){
        const int lrow = lrow0 + rt*16 + lr;
        const float* xr = xs + lrow*XPITCH + lh*8;
        const float4 xa0 = *(const float4*)(xr);
        const float4 xa1 = *(const float4*)(xr + 4);
        const float4 xb0 = *(const float4*)(xr + 32);
        const float4 xb1 = *(const float4*)(xr + 36);
        FragH b0, b1;
        b0.u[0]=cvt2h(xa0.x,xa0.y); b0.u[1]=cvt2h(xa0.z,xa0.w);
        b0.u[2]=cvt2h(xa1.x,xa1.y); b0.u[3]=cvt2h(xa1.z,xa1.w);
        b1.u[0]=cvt2h(xb0.x,xb0.y); b1.u[1]=cvt2h(xb0.z,xb0.w);
        b1.u[2]=cvt2h(xb1.x,xb1.y); b1.u[3]=cvt2h(xb1.z,xb1.w);

        const size_t row = (size_t)blockIdx.x*128 + lrow;
        #pragma unroll
        for (int ft=0;ft<4;ft++){
            float4v aA = float4v{biasA[ft].x, biasA[ft].y, biasA[ft].z, biasA[ft].w};
            aA = __builtin_amdgcn_mfma_f32_16x16x32_f16(afA[ft][0].h, b0.h, aA, 0,0,0);
            aA = __builtin_amdgcn_mfma_f32_16x16x32_f16(afA[ft][1].h, b1.h, aA, 0,0,0);
            float4v aB = float4v{biasB[ft].x, biasB[ft].y, biasB[ft].z, biasB[ft].w};
            aB = __builtin_amdgcn_mfma_f32_16x16x32_f16(afB[ft][0].h, b0.h, aB, 0,0,0);
            aB = __builtin_amdgcn_mfma_f32_16x16x32_f16(afB[ft][1].h, b1.h, aB, 0,0,0);
            if (wm == 0){
                uint2 st; st.x = cvt2h(aA[0],aA[1]); st.y = cvt2h(aA[2],aA[3]);
                *(uint2*)(Kh + row*32 + ft*8 + lh*2) = st;
                *(float4*)(out + row*FF + ft*16 + lh*4) =
                    make_float4(aB[0],aB[1],aB[2],aB[3]);
            } else {
                uint4 st;
                st.x = cvt2h(aA[0],aA[1]); st.y = cvt2h(aB[0],aB[1]);
                st.z = cvt2h(aA[2],aA[3]); st.w = cvt2h(aB[2],aB[3]);
                *(uint4*)(QV + row*FF + ft*16 + lh*4) = st;
            }
        }
    }
}

// ---------------- Kernel 2: gather + gate + aggregate (fp16, 2 bt/wave) --
#define HEDGE2(U, KA, KB, A01, A23) { \
    half2v g01 = (KA) + h2((U).x); \
    g01 = __builtin_elementwise_max(g01, g01*c001); \
    (A01) += g01 * h2((U).y); \
    half2v g23 = (KB) + h2((U).z); \
    g23 = __builtin_elementwise_max(g23, g23*c001); \
    (A23) += g23 * h2((U).w); }
#define HEDGE2M(U, KA, KB, A01, A23, M) { \
    half2v g01 = (KA) + h2((U).x); \
    g01 = __builtin_elementwise_max(g01, g01*c001); \
    (A01) += g01 * (h2((U).y) * (M)); \
    half2v g23 = (KB) + h2((U).z); \
    g23 = __builtin_elementwise_max(g23, g23*c001); \
    (A23) += g23 * (h2((U).w) * (M)); }

__global__ __launch_bounds__(256) void agg_kernel(
    const unsigned* __restrict__ Kh, const unsigned* __restrict__ QV,
    const int* __restrict__ offs, const int* __restrict__ elist,
    float* __restrict__ out)
{
    const int tid  = threadIdx.x;
    const int lane = tid & 63;
    const int w    = tid >> 6;
    const int b    = blockIdx.x;          // 12288 blocks
    const int xcd  = b & 7;
    const int li   = b >> 3;              // 0..1535
    const int pr   = xcd*3 + (li >> 9);   // bt pair 0..23
    const int node = ((li & 511) << 2) | w;
    const int sub  = lane >> 4;
    const int fq   = lane & 15;
    const int bt0  = pr*2;
    const size_t S = (size_t)NN*FF;

    const uint2 ku0 = *(const uint2*)(Kh + ((size_t)bt0*NN + node)*32 + 2*fq);
    const uint2 ku1 = *(const uint2*)(Kh + ((size_t)(bt0+1)*NN + node)*32 + 2*fq);
    const size_t r0 = ((size_t)bt0*NN + node)*FF;
    const size_t r1 = r0 + S;
    const float4 sk0 = *(const float4*)(out + r0 + fq*4);
    const float4 sk1 = *(const float4*)(out + r1 + fq*4);

    const half2v k01a = h2(ku0.x), k23a = h2(ku0.y);
    const half2v k01b = h2(ku1.x), k23b = h2(ku1.y);
    const half2v c001 = half2v{(_Float16)0.01f, (_Float16)0.01f};
    const half2v one2 = half2v{(_Float16)1.f, (_Float16)1.f};
    const half2v zero2 = half2v{(_Float16)0.f, (_Float16)0.f};
    const unsigned* QV0 = QV + (size_t)bt0*S;
    const unsigned* QV1 = QV0 + S;

    half2v a01_0 = zero2, a23_0 = zero2;  // bt0
    half2v a01_1 = zero2, a23_1 = zero2;  // bt1
    const int s0 = offs[node], s1 = offs[node+1];

    for (int i = s0; i < s1; i += 16){
        const int rem  = s1 - i;          // wave-uniform
        const int4 ev = *(const int4*)(elist + i + 4*sub);
        const unsigned o0 = (((unsigned)ev.x)<<6) + (fq<<2);
        const unsigned o1 = (((unsigned)ev.y)<<6) + (fq<<2);
        const unsigned o2 = (((unsigned)ev.z)<<6) + (fq<<2);
        const unsigned o3 = (((unsigned)ev.w)<<6) + (fq<<2);
        const uint4 u00 = *(const uint4*)(QV0 + o0);
        const uint4 u10 = *(const uint4*)(QV1 + o0);
        const uint4 u01 = *(const uint4*)(QV0 + o1);
        const uint4 u11 = *(const uint4*)(QV1 + o1);
        const uint4 u02 = *(const uint4*)(QV0 + o2);
        const uint4 u12 = *(const uint4*)(QV1 + o2);
        const uint4 u03 = *(const uint4*)(QV0 + o3);
        const uint4 u13 = *(const uint4*)(QV1 + o3);
        if (rem >= 16){
            HEDGE2(u00, k01a, k23a, a01_0, a23_0); HEDGE2(u10, k01b, k23b, a01_1, a23_1);
            HEDGE2(u01, k01a, k23a, a01_0, a23_0); HEDGE2(u11, k01b, k23b, a01_1, a23_1);
            HEDGE2(u02, k01a, k23a, a01_0, a23_0); HEDGE2(u12, k01b, k23b, a01_1, a23_1);
            HEDGE2(u03, k01a, k23a, a01_0, a23_0); HEDGE2(u13, k01b, k23b, a01_1, a23_1);
        } else {
            const half2v m0 = (4*sub+0 < rem) ? one2 : zero2;
            const half2v m1 = (4*sub+1 < rem) ? one2 : zero2;
            const half2v m2 = (4*sub+2 < rem) ? one2 : zero2;
            const half2v m3 = (4*sub+3 < rem) ? one2 : zero2;
            HEDGE2M(u00, k01a, k23a, a01_0, a23_0, m0); HEDGE2M(u10, k01b, k23b, a01_1, a23_1, m0);
            HEDGE2M(u01, k01a, k23a, a01_0, a23_0, m1); HEDGE2M(u11, k01b, k23b, a01_1, a23_1, m1);
            HEDGE2M(u02, k01a, k23a, a01_0, a23_0, m2); HEDGE2M(u12, k01b, k23b, a01_1, a23_1, m2);
            HEDGE2M(u03, k01a, k23a, a01_0, a23_0, m3); HEDGE2M(u13, k01b, k23b, a01_1, a23_1, m3);
        }
    }

    float4 ac0 = make_float4((float)a01_0[0], (float)a01_0[1],
                             (float)a23_0[0], (float)a23_0[1]);
    float4 ac1 = make_float4((float)a01_1[0], (float)a01_1[1],
                             (float)a23_1[0], (float)a23_1[1]);

    ac0.x += __shfl_xor(ac0.x, 16, 64); ac0.y += __shfl_xor(ac0.y, 16, 64);
    ac0.z += __shfl_xor(ac0.z, 16, 64); ac0.w += __shfl_xor(ac0.w, 16, 64);
    ac0.x += __shfl_xor(ac0.x, 32, 64); ac0.y += __shfl_xor(ac0.y, 32, 64);
    ac0.z += __shfl_xor(ac0.z, 32, 64); ac0.w += __shfl_xor(ac0.w, 32, 64);
    ac1.x += __shfl_xor(ac1.x, 16, 64); ac1.y += __shfl_xor(ac1.y, 16, 64);
    ac1.z += __shfl_xor(ac1.z, 16, 64); ac1.w += __shfl_xor(ac1.w, 16, 64);
    ac1.x += __shfl_xor(ac1.x, 32, 64); ac1.y += __shfl_xor(ac1.y, 32, 64);
    ac1.z += __shfl_xor(ac1.z, 32, 64); ac1.w += __shfl_xor(ac1.w, 32, 64);

    if (sub == 0){
        *(float4*)(out + r0 + fq*4) =
            make_float4(ac0.x+sk0.x, ac0.y+sk0.y, ac0.z+sk0.z, ac0.w+sk0.w);
        *(float4*)(out + r1 + fq*4) =
            make_float4(ac1.x+sk1.x, ac1.y+sk1.y, ac1.z+sk1.z, ac1.w+sk1.w);
    }
}

extern "C" void kernel_launch(void* const* d_in, const int* in_sizes, int n_in,
                              void* d_out, int out_size, void* d_ws, size_t ws_size,
                              hipStream_t stream)
{
    const float* x  = (const float*)d_in[0];
    const unsigned int* ew = (const unsigned int*)d_in[1];
    const float* Wk = (const float*)d_in[2];
    const float* bk = (const float*)d_in[3];
    const float* Wq = (const float*)d_in[4];
    const float* bq = (const float*)d_in[5];
    const float* Wv = (const float*)d_in[6];
    const float* bv = (const float*)d_in[7];
    const float* Ws = (const float*)d_in[8];
    const float* bs = (const float*)d_in[9];
    float* out = (float*)d_out;

    const size_t n = (size_t)ROWS*FF;
    unsigned* Kh = (unsigned*)d_ws;       // ROWS*32 u32
    unsigned* QV = Kh + (size_t)ROWS*32;  // ROWS*64 u32
    unsigned* Wp = QV + n;                // 8192 u32
    int* meta  = (int*)(Wp + 8192);
    int* flag  = meta;
    int* bar   = meta + 4;
    int* deg   = meta + 16;
    int* offs  = deg + NN;
    int* cur   = offs + NN + 16;
    int* elist = cur + NN;

    hipLaunchKernelGGL(wpack_kernel, dim3(1), dim3(256), 0, stream,
                       Wk, Wq, Wv, Ws, Wp, meta);
    hipLaunchKernelGGL(projcsr_kernel, dim3(PROJ_BLKS + CSR_BLKS), dim3(256), 0, stream,
                       x, Wp, bk, bq, bv, bs, Kh, QV, out,
                       ew, flag, bar, deg, offs, cur, elist);
    hipLaunchKernelGGL(agg_kernel, dim3(ROWS/8), dim3(256), 0, stream,
                       Kh, QV, offs, elist, out);
}

// Round 20
// 90.992 us; speedup vs baseline: 1.1322x; 1.0232x over previous
//
#include <hip/hip_runtime.h>

#define BT 48
#define NN 2048
#define FF 64
#define EE 32768
#define ROWS (BT*NN)          // 98304
#define PROJ_BLKS 768         // 128 rows each
#define CSR_BLKS 64
#define XPITCH 68             // LDS row pitch (floats): breaks 256B-stride bank conflicts

typedef __attribute__((ext_vector_type(2))) _Float16 half2v;
typedef __attribute__((ext_vector_type(8))) _Float16 half8v;
typedef __attribute__((ext_vector_type(4))) float float4v;

__device__ __forceinline__ unsigned cvt2h(float lo, float hi){
    union { half2v h; unsigned u; } c;
    c.h = half2v{(_Float16)lo, (_Float16)hi};
    return c.u;
}
__device__ __forceinline__ half2v h2(unsigned u){
    union { unsigned u; half2v h; } c; c.u = u; return c.h;
}

union FragH { unsigned u[4]; half8v h; uint4 u4; };

// ---------------- Kernel 0: W fragment pre-pack (+ meta zero) ----------
__global__ __launch_bounds__(256) void wpack_kernel(
    const float* __restrict__ Wk, const float* __restrict__ Wq,
    const float* __restrict__ Wv, const float* __restrict__ Ws,
    unsigned* __restrict__ Wp, int* __restrict__ meta)
{
    const int t = threadIdx.x;
    if (t < 8) meta[t] = 0;
    for (int idx = t; idx < 8192; idx += 256){
        const int mat = idx >> 11;
        const int r   = idx & 2047;
        const int ft  = r >> 9;
        const int h   = (r >> 8) & 1;
        const int l   = (r >> 2) & 63;
        const int jj  = r & 3;
        const float* W = (mat==0)?Wk:(mat==1)?Wq:(mat==2)?Wv:Ws;
        const int k0 = h*32 + (l>>4)*8 + 2*jj;
        const int c  = ft*16 + (l&15);
        Wp[idx] = cvt2h(W[(size_t)k0*FF + c], W[(size_t)(k0+1)*FF + c]);
    }
}

// ---------------- Kernel 1: proj (blocks 0..767) + CSR (768..831) -------
// R20 = R17 + asm-volatile PIN of the 16 W fragments. R11-R18's proj
// plateau (46-52us, VALUBusy 3%, VGPR_Count 48-72 < fragment footprint)
// is the compiler REMATERIALIZING fragments from global Wp inside the
// MFMA loop (legal for const-restrict loads) at L2 latency. An empty
// asm volatile("" : "+v"(word)) makes each fragment word opaque -- the
// compiler can no longer re-derive it from memory and must keep it
// register-resident.
__device__ __forceinline__ void gbar(int* ctr, int nblk){
    __syncthreads();
    if (threadIdx.x == 0){
        __threadfence();
        atomicAdd(ctr, 1);
        while (__hip_atomic_load(ctr, __ATOMIC_ACQUIRE, __HIP_MEMORY_SCOPE_AGENT) < nblk) {}
    }
    __syncthreads();
}

__global__ __launch_bounds__(256, 4) void projcsr_kernel(
    const float* __restrict__ x, const unsigned* __restrict__ Wp,
    const float* __restrict__ bk, const float* __restrict__ bq,
    const float* __restrict__ bv, const float* __restrict__ bs,
    unsigned* __restrict__ Kh, unsigned* __restrict__ QV,
    float* __restrict__ out,
    const unsigned int* __restrict__ ew,
    int* __restrict__ flag, int* __restrict__ bar,
    int* __restrict__ deg, int* __restrict__ offs,
    int* __restrict__ cur, int* __restrict__ elist)
{
    __shared__ float xs[128*XPITCH];      // 34 KB
    __shared__ int wsums[4];

    if (blockIdx.x >= PROJ_BLKS){
        // ---------------- CSR part ----------------
        const int t = threadIdx.x;
        const int gtid = (blockIdx.x - PROJ_BLKS)*256 + t;   // 16384 threads

        for (int i=gtid; i<NN; i+=16384) deg[i] = 0;
        if (gtid < 16) elist[EE + gtid] = 0;
        unsigned f = 0;
        for (int i=gtid; i<8192; i+=16384) f |= ew[2*i+1];
        if (f) atomicOr((unsigned int*)flag, f);
        gbar(bar+0, CSR_BLKS);
        const bool i64 = (*flag == 0);

        for (int e=gtid; e<EE; e+=16384){
            const int d = i64 ? (int)ew[2*(EE+e)] : (int)ew[EE+e];
            atomicAdd(&deg[d], 1);
        }
        gbar(bar+1, CSR_BLKS);

        if (blockIdx.x == PROJ_BLKS){
            const int base = t*8;
            int v[8], pre[8];
            #pragma unroll
            for (int j=0;j<8;j++) v[j] = deg[base+j];
            pre[0] = 0;
            #pragma unroll
            for (int j=1;j<8;j++) pre[j] = pre[j-1] + v[j-1];
            const int s = pre[7] + v[7];
            int inc = s;
            const int lane = t & 63, wid = t >> 6;
            #pragma unroll
            for (int d=1; d<64; d<<=1){ int tt = __shfl_up(inc, d, 64); if (lane>=d) inc += tt; }
            if (lane == 63) wsums[wid] = inc;
            __syncthreads();
            if (t == 0){ int a=0; for (int k2=0;k2<4;k2++){ int tt=wsums[k2]; wsums[k2]=a; a+=tt; } }
            __syncthreads();
            const int excl = wsums[wid] + (inc - s);
            #pragma unroll
            for (int j=0;j<8;j++){ offs[base+j] = excl + pre[j]; cur[base+j] = excl + pre[j]; }
            if (t == 255) offs[NN] = excl + s;
        }
        gbar(bar+2, CSR_BLKS);

        for (int e=gtid; e<EE; e+=16384){
            int d, s;
            if (i64){ d = (int)ew[2*(EE+e)]; s = (int)ew[2*e]; }
            else    { d = (int)ew[EE+e];     s = (int)ew[e];   }
            const int pos = atomicAdd(&cur[d], 1);
            elist[pos] = s;
        }
        return;
    }

    // ---------------- proj part ----------------
    const int tid = threadIdx.x;
    const int w  = tid >> 6;
    const int l  = tid & 63;
    const int lr = l & 15;
    const int lh = l >> 4;
    const int wm = w & 1;                 // 0: K+skip, 1: Q+V
    const int matA = wm ? 1 : 0;          // Q : K
    const int matB = wm ? 2 : 3;          // V : skip
    const float* bmA = wm ? bq : bk;
    const float* bmB = wm ? bv : bs;

    // stage 128 rows of x into LDS (coalesced)
    {
        const float4* xg = (const float4*)(x + (size_t)blockIdx.x*128*FF);
        for (int i = tid; i < 128*16; i += 256){
            const int row = i >> 4, c4 = i & 15;
            *(float4*)(xs + row*XPITCH + c4*4) = xg[i];
        }
    }

    FragH afA[4][2], afB[4][2];
    #pragma unroll
    for (int ft=0;ft<4;ft++)
        #pragma unroll
        for (int h=0;h<2;h++){
            afA[ft][h].u4 = *(const uint4*)(Wp + ((matA*4+ft)*2+h)*256 + l*4);
            afB[ft][h].u4 = *(const uint4*)(Wp + ((matB*4+ft)*2+h)*256 + l*4);
        }
    // PIN: make each fragment word opaque so the compiler cannot
    // rematerialize it from Wp inside the loop (must stay in VGPRs).
    #pragma unroll
    for (int ft=0;ft<4;ft++)
        #pragma unroll
        for (int h=0;h<2;h++){
            asm volatile("" : "+v"(afA[ft][h].u[0]), "+v"(afA[ft][h].u[1]),
                              "+v"(afA[ft][h].u[2]), "+v"(afA[ft][h].u[3]));
            asm volatile("" : "+v"(afB[ft][h].u[0]), "+v"(afB[ft][h].u[1]),
                              "+v"(afB[ft][h].u[2]), "+v"(afB[ft][h].u[3]));
        }

    float4 biasA[4], biasB[4];
    #pragma unroll
    for (int ft=0;ft<4;ft++){
        biasA[ft] = *(const float4*)(bmA + ft*16 + lh*4);
        biasB[ft] = *(const float4*)(bmB + ft*16 + lh*4);
    }
    __syncthreads();

    const int lrow0 = (w>>1)*64;
    #pragma unroll 2
    for (int rt=0; rt<4; ++rt){
        const int lrow = lrow0 + rt*16 + lr;
        const float* xr = xs + lrow*XPITCH + lh*8;
        const float4 xa0 = *(const float4*)(xr);
        const float4 xa1 = *(const float4*)(xr + 4);
        const float4 xb0 = *(const float4*)(xr + 32);
        const float4 xb1 = *(const float4*)(xr + 36);
        FragH b0, b1;
        b0.u[0]=cvt2h(xa0.x,xa0.y); b0.u[1]=cvt2h(xa0.z,xa0.w);
        b0.u[2]=cvt2h(xa1.x,xa1.y); b0.u[3]=cvt2h(xa1.z,xa1.w);
        b1.u[0]=cvt2h(xb0.x,xb0.y); b1.u[1]=cvt2h(xb0.z,xb0.w);
        b1.u[2]=cvt2h(xb1.x,xb1.y); b1.u[3]=cvt2h(xb1.z,xb1.w);

        const size_t row = (size_t)blockIdx.x*128 + lrow;
        #pragma unroll
        for (int ft=0;ft<4;ft++){
            float4v aA = float4v{biasA[ft].x, biasA[ft].y, biasA[ft].z, biasA[ft].w};
            aA = __builtin_amdgcn_mfma_f32_16x16x32_f16(afA[ft][0].h, b0.h, aA, 0,0,0);
            aA = __builtin_amdgcn_mfma_f32_16x16x32_f16(afA[ft][1].h, b1.h, aA, 0,0,0);
            float4v aB = float4v{biasB[ft].x, biasB[ft].y, biasB[ft].z, biasB[ft].w};
            aB = __builtin_amdgcn_mfma_f32_16x16x32_f16(afB[ft][0].h, b0.h, aB, 0,0,0);
            aB = __builtin_amdgcn_mfma_f32_16x16x32_f16(afB[ft][1].h, b1.h, aB, 0,0,0);
            if (wm == 0){
                uint2 st; st.x = cvt2h(aA[0],aA[1]); st.y = cvt2h(aA[2],aA[3]);
                *(uint2*)(Kh + row*32 + ft*8 + lh*2) = st;
                *(float4*)(out + row*FF + ft*16 + lh*4) =
                    make_float4(aB[0],aB[1],aB[2],aB[3]);
            } else {
                uint4 st;
                st.x = cvt2h(aA[0],aA[1]); st.y = cvt2h(aB[0],aB[1]);
                st.z = cvt2h(aA[2],aA[3]); st.w = cvt2h(aB[2],aB[3]);
                *(uint4*)(QV + row*FF + ft*16 + lh*4) = st;
            }
        }
    }
}

// ---------------- Kernel 2: gather + gate + aggregate (fp16, 2 bt/wave) --
#define HEDGE2(U, KA, KB, A01, A23) { \
    half2v g01 = (KA) + h2((U).x); \
    g01 = __builtin_elementwise_max(g01, g01*c001); \
    (A01) += g01 * h2((U).y); \
    half2v g23 = (KB) + h2((U).z); \
    g23 = __builtin_elementwise_max(g23, g23*c001); \
    (A23) += g23 * h2((U).w); }
#define HEDGE2M(U, KA, KB, A01, A23, M) { \
    half2v g01 = (KA) + h2((U).x); \
    g01 = __builtin_elementwise_max(g01, g01*c001); \
    (A01) += g01 * (h2((U).y) * (M)); \
    half2v g23 = (KB) + h2((U).z); \
    g23 = __builtin_elementwise_max(g23, g23*c001); \
    (A23) += g23 * (h2((U).w) * (M)); }

__global__ __launch_bounds__(256) void agg_kernel(
    const unsigned* __restrict__ Kh, const unsigned* __restrict__ QV,
    const int* __restrict__ offs, const int* __restrict__ elist,
    float* __restrict__ out)
{
    const int tid  = threadIdx.x;
    const int lane = tid & 63;
    const int w    = tid >> 6;
    const int b    = blockIdx.x;          // 12288 blocks
    const int xcd  = b & 7;
    const int li   = b >> 3;              // 0..1535
    const int pr   = xcd*3 + (li >> 9);   // bt pair 0..23
    const int node = ((li & 511) << 2) | w;
    const int sub  = lane >> 4;
    const int fq   = lane & 15;
    const int bt0  = pr*2;
    const size_t S = (size_t)NN*FF;

    const uint2 ku0 = *(const uint2*)(Kh + ((size_t)bt0*NN + node)*32 + 2*fq);
    const uint2 ku1 = *(const uint2*)(Kh + ((size_t)(bt0+1)*NN + node)*32 + 2*fq);
    const size_t r0 = ((size_t)bt0*NN + node)*FF;
    const size_t r1 = r0 + S;
    const float4 sk0 = *(const float4*)(out + r0 + fq*4);
    const float4 sk1 = *(const float4*)(out + r1 + fq*4);

    const half2v k01a = h2(ku0.x), k23a = h2(ku0.y);
    const half2v k01b = h2(ku1.x), k23b = h2(ku1.y);
    const half2v c001 = half2v{(_Float16)0.01f, (_Float16)0.01f};
    const half2v one2 = half2v{(_Float16)1.f, (_Float16)1.f};
    const half2v zero2 = half2v{(_Float16)0.f, (_Float16)0.f};
    const unsigned* QV0 = QV + (size_t)bt0*S;
    const unsigned* QV1 = QV0 + S;

    half2v a01_0 = zero2, a23_0 = zero2;  // bt0
    half2v a01_1 = zero2, a23_1 = zero2;  // bt1
    const int s0 = offs[node], s1 = offs[node+1];

    for (int i = s0; i < s1; i += 16){
        const int rem  = s1 - i;          // wave-uniform
        const int4 ev = *(const int4*)(elist + i + 4*sub);
        const unsigned o0 = (((unsigned)ev.x)<<6) + (fq<<2);
        const unsigned o1 = (((unsigned)ev.y)<<6) + (fq<<2);
        const unsigned o2 = (((unsigned)ev.z)<<6) + (fq<<2);
        const unsigned o3 = (((unsigned)ev.w)<<6) + (fq<<2);
        const uint4 u00 = *(const uint4*)(QV0 + o0);
        const uint4 u10 = *(const uint4*)(QV1 + o0);
        const uint4 u01 = *(const uint4*)(QV0 + o1);
        const uint4 u11 = *(const uint4*)(QV1 + o1);
        const uint4 u02 = *(const uint4*)(QV0 + o2);
        const uint4 u12 = *(const uint4*)(QV1 + o2);
        const uint4 u03 = *(const uint4*)(QV0 + o3);
        const uint4 u13 = *(const uint4*)(QV1 + o3);
        if (rem >= 16){
            HEDGE2(u00, k01a, k23a, a01_0, a23_0); HEDGE2(u10, k01b, k23b, a01_1, a23_1);
            HEDGE2(u01, k01a, k23a, a01_0, a23_0); HEDGE2(u11, k01b, k23b, a01_1, a23_1);
            HEDGE2(u02, k01a, k23a, a01_0, a23_0); HEDGE2(u12, k01b, k23b, a01_1, a23_1);
            HEDGE2(u03, k01a, k23a, a01_0, a23_0); HEDGE2(u13, k01b, k23b, a01_1, a23_1);
        } else {
            const half2v m0 = (4*sub+0 < rem) ? one2 : zero2;
            const half2v m1 = (4*sub+1 < rem) ? one2 : zero2;
            const half2v m2 = (4*sub+2 < rem) ? one2 : zero2;
            const half2v m3 = (4*sub+3 < rem) ? one2 : zero2;
            HEDGE2M(u00, k01a, k23a, a01_0, a23_0, m0); HEDGE2M(u10, k01b, k23b, a01_1, a23_1, m0);
            HEDGE2M(u01, k01a, k23a, a01_0, a23_0, m1); HEDGE2M(u11, k01b, k23b, a01_1, a23_1, m1);
            HEDGE2M(u02, k01a, k23a, a01_0, a23_0, m2); HEDGE2M(u12, k01b, k23b, a01_1, a23_1, m2);
            HEDGE2M(u03, k01a, k23a, a01_0, a23_0, m3); HEDGE2M(u13, k01b, k23b, a01_1, a23_1, m3);
        }
    }

    float4 ac0 = make_float4((float)a01_0[0], (float)a01_0[1],
                             (float)a23_0[0], (float)a23_0[1]);
    float4 ac1 = make_float4((float)a01_1[0], (float)a01_1[1],
                             (float)a23_1[0], (float)a23_1[1]);

    ac0.x += __shfl_xor(ac0.x, 16, 64); ac0.y += __shfl_xor(ac0.y, 16, 64);
    ac0.z += __shfl_xor(ac0.z, 16, 64); ac0.w += __shfl_xor(ac0.w, 16, 64);
    ac0.x += __shfl_xor(ac0.x, 32, 64); ac0.y += __shfl_xor(ac0.y, 32, 64);
    ac0.z += __shfl_xor(ac0.z, 32, 64); ac0.w += __shfl_xor(ac0.w, 32, 64);
    ac1.x += __shfl_xor(ac1.x, 16, 64); ac1.y += __shfl_xor(ac1.y, 16, 64);
    ac1.z += __shfl_xor(ac1.z, 16, 64); ac1.w += __shfl_xor(ac1.w, 16, 64);
    ac1.x += __shfl_xor(ac1.x, 32, 64); ac1.y += __shfl_xor(ac1.y, 32, 64);
    ac1.z += __shfl_xor(ac1.z, 32, 64); ac1.w += __shfl_xor(ac1.w, 32, 64);

    if (sub == 0){
        *(float4*)(out + r0 + fq*4) =
            make_float4(ac0.x+sk0.x, ac0.y+sk0.y, ac0.z+sk0.z, ac0.w+sk0.w);
        *(float4*)(out + r1 + fq*4) =
            make_float4(ac1.x+sk1.x, ac1.y+sk1.y, ac1.z+sk1.z, ac1.w+sk1.w);
    }
}

extern "C" void kernel_launch(void* const* d_in, const int* in_sizes, int n_in,
                              void* d_out, int out_size, void* d_ws, size_t ws_size,
                              hipStream_t stream)
{
    const float* x  = (const float*)d_in[0];
    const unsigned int* ew = (const unsigned int*)d_in[1];
    const float* Wk = (const float*)d_in[2];
    const float* bk = (const float*)d_in[3];
    const float* Wq = (const float*)d_in[4];
    const float* bq = (const float*)d_in[5];
    const float* Wv = (const float*)d_in[6];
    const float* bv = (const float*)d_in[7];
    const float* Ws = (const float*)d_in[8];
    const float* bs = (const float*)d_in[9];
    float* out = (float*)d_out;

    const size_t n = (size_t)ROWS*FF;
    unsigned* Kh = (unsigned*)d_ws;       // ROWS*32 u32
    unsigned* QV = Kh + (size_t)ROWS*32;  // ROWS*64 u32
    unsigned* Wp = QV + n;                // 8192 u32
    int* meta  = (int*)(Wp + 8192);
    int* flag  = meta;
    int* bar   = meta + 4;
    int* deg   = meta + 16;
    int* offs  = deg + NN;
    int* cur   = offs + NN + 16;
    int* elist = cur + NN;

    hipLaunchKernelGGL(wpack_kernel, dim3(1), dim3(256), 0, stream,
                       Wk, Wq, Wv, Ws, Wp, meta);
    hipLaunchKernelGGL(projcsr_kernel, dim3(PROJ_BLKS + CSR_BLKS), dim3(256), 0, stream,
                       x, Wp, bk, bq, bv, bs, Kh, QV, out,
                       ew, flag, bar, deg, offs, cur, elist);
    hipLaunchKernelGGL(agg_kernel, dim3(ROWS/8), dim3(256), 0, stream,
                       Kh, QV, offs, elist, out);
}